// Round 7
// baseline (263.149 us; speedup 1.0000x reference)
//
#include <hip/hip_runtime.h>
#include <cstdint>
#include <cstddef>

#define NROWS 8192
#define DIM   25
#define CIN   128
#define COUT  128
#define MAXT  160

// ---------------- compile-time path tables (mirrors reference _build_paths) --
struct Tables {
  int   w_idx[MAXT];     // per original entry t: weight row
  float coef[MAXT];      // per original entry t: signed coefficient
  int   o_start[DIM + 1];
  int   e_in[MAXT];      // bucketed-by-o: input DIM row
  int   e_t[MAXT];       // bucketed-by-o: original entry index (row of Bt)
  int   o_lpt[DIM];      // o indices sorted by descending entry count (LPT)
  int   T;
};

constexpr Tables build_tables() {
  Tables tb{};
  int off[5] = {0, 1, 4, 9, 16};
  const float pn = 0.44721359549995793f;  // 1/sqrt(5)
  int in_idx[MAXT] = {}, out_idx[MAXT] = {}, widx[MAXT] = {};
  float cf[MAXT] = {};
  int T = 0, w = 0;
  for (int lo = 0; lo < 5; ++lo) {
    for (int li = 0; li < 5; ++li) {
      int oi = off[li], oo = off[lo];
      in_idx[T] = oi + li; out_idx[T] = oo + lo; widx[T] = w; cf[T] = pn; ++T; ++w;
      int mm = li < lo ? li : lo;
      for (int m = 1; m <= mm; ++m) {
        int ip = oi + li + m, im = oi + li - m;
        int op = oo + lo + m, om = oo + lo - m;
        int wre = w, wim = w + 1; w += 2;
        in_idx[T] = ip; out_idx[T] = op; widx[T] = wre; cf[T] = pn;  ++T;
        in_idx[T] = im; out_idx[T] = om; widx[T] = wre; cf[T] = pn;  ++T;
        in_idx[T] = ip; out_idx[T] = om; widx[T] = wim; cf[T] = pn;  ++T;
        in_idx[T] = im; out_idx[T] = op; widx[T] = wim; cf[T] = -pn; ++T;
      }
    }
  }
  tb.T = T;  // 145
  for (int t = 0; t < T; ++t) { tb.w_idx[t] = widx[t]; tb.coef[t] = cf[t]; }
  int pos = 0;
  for (int o = 0; o < DIM; ++o) {
    tb.o_start[o] = pos;
    for (int t = 0; t < T; ++t)
      if (out_idx[t] == o) { tb.e_in[pos] = in_idx[t]; tb.e_t[pos] = t; ++pos; }
  }
  tb.o_start[DIM] = pos;
  // LPT order: heavy o (nIter up to 16) first within each n-tile group.
  for (int i = 0; i < DIM; ++i) tb.o_lpt[i] = i;
  for (int i = 0; i < DIM; ++i) {
    int best = i;
    for (int j = i + 1; j < DIM; ++j) {
      int nb = tb.o_start[tb.o_lpt[best] + 1] - tb.o_start[tb.o_lpt[best]];
      int nj = tb.o_start[tb.o_lpt[j] + 1] - tb.o_start[tb.o_lpt[j]];
      if (nj > nb) best = j;
    }
    int tmp = tb.o_lpt[i]; tb.o_lpt[i] = tb.o_lpt[best]; tb.o_lpt[best] = tmp;
  }
  return tb;
}

__constant__ Tables TAB = build_tables();

// ---------------- helpers ----------------------------------------------------
__device__ __forceinline__ uint16_t f2bf(float f) {
  uint32_t u = __float_as_uint(f);
  uint32_t r = (u + 0x7FFFu + ((u >> 16) & 1u)) >> 16;
  return (uint16_t)r;
}

__device__ __forceinline__ void load_lds16(const void* g, void* l) {
  __builtin_amdgcn_global_load_lds(
      (const __attribute__((address_space(1))) uint32_t*)g,
      (__attribute__((address_space(3))) uint32_t*)l, 16, 0, 0);
}

typedef __bf16 v8bf __attribute__((ext_vector_type(8)));
typedef float  v4f  __attribute__((ext_vector_type(4)));

// pack two float4 into 8 bf16 (compiler emits v_cvt_pk_bf16_f32 — RNE)
__device__ __forceinline__ v8bf cvt8(float4 p, float4 q) {
  v8bf v;
  v[0] = (__bf16)p.x; v[1] = (__bf16)p.y; v[2] = (__bf16)p.z; v[3] = (__bf16)p.w;
  v[4] = (__bf16)q.x; v[5] = (__bf16)q.y; v[6] = (__bf16)q.z; v[7] = (__bf16)q.w;
  return v;
}

// ---------------- kernel 1: weight prep only ---------------------------------
// LDS-tiled transpose+scale of weights: Bt[t][d][c] = coef[t]*W[w_idx[t]][c][d]
// 4 blocks per t (32 d each). ~7 MB traffic -> a few microseconds.
#define NWB  (145 * 4)

__global__ void prep_kernel(const float* __restrict__ W, uint16_t* __restrict__ Bt) {
  __shared__ float tile[128][33];
  int b  = blockIdx.x;
  int t  = b >> 2;
  int d0 = (b & 3) << 5;                  // 32 d-values per block
  int w  = TAB.w_idx[t];
  float cf = TAB.coef[t];
  const float* Wp = W + (size_t)w * CIN * COUT;
  uint16_t* Bp = Bt + (size_t)t * CIN * COUT;
  int tid = threadIdx.x;
  {
    int dcol = tid & 31, cbase = tid >> 5;     // 8 c-rows per pass
    #pragma unroll
    for (int r = 0; r < 16; ++r) {
      int c = (r << 3) + cbase;
      tile[c][dcol] = cf * Wp[(size_t)c * COUT + d0 + dcol];
    }
  }
  __syncthreads();
  {
    int c = tid & 127, dbase = tid >> 7;       // 2 d-rows per pass
    #pragma unroll
    for (int r = 0; r < 16; ++r) {
      int dd = (r << 1) + dbase;
      Bp[(size_t)(d0 + dd) * CIN + c] = f2bf(tile[c][dd]);
    }
  }
}

// ---------------- kernel 2: fused-dtype grouped GEMM -------------------------
// Per block: Out[n0..n0+255][o][0..127] = sum_e X[n][IN[e]][:] . Bt[e_t][:][:]
// Round-7: round-6 skeleton EXACTLY (BM=256, 8 waves, single-buffer,
// 2 barriers/K-step, LPT order, XCD swizzle) with the A path reading fp32 X
// DIRECTLY (prep's 157 MB cast pass deleted):
//   - A staged as fp32 via global_load_lds (16B = 4 floats/lane), same XOR
//     chunk swizzle (16 chunks/row; <=2-way alias = free, like the proven
//     bf16 scheme). As = 64 KB fp32.
//   - fragment read: 2x float4 ds_read + cvt8 (4x v_cvt_pk_bf16_f32). cvt
//     rides the ds_read->MFMA path — no serial section (r4's killer), no reg
//     round-trip for staging (r3's killer), VALU overlaps MFMA (sep. pipes).
//   - LDS 64+16 = 80 KB -> still 2 blocks/CU (residency rule: never <2).
// Diagnostic: FETCH_SIZE tells whether 3.3 MB fp32 slabs thrash XCD-L2.
__global__ __launch_bounds__(512) void so2_gemm(
    const float* __restrict__ X,       // [NROWS][DIM][CIN] fp32
    const uint16_t* __restrict__ Bt,   // [T][COUT][CIN]    bf16 bits
    float* __restrict__ Out) {         // [NROWS][DIM][COUT]
  __shared__ __align__(16) float    Asf[256 * 64];  // 64 KB fp32
  __shared__ __align__(16) uint16_t Bs[128 * 64];   // 16 KB bf16

  // XCD-aware decode: lb -> (o, n-tile), LPT-permuted o within each group
  const int lb   = blockIdx.x;            // 0..799
  const int xcd  = lb & 7;
  const int slot = lb >> 3;               // 0..99
  const int o    = TAB.o_lpt[slot % 25];  // heavy o first within an XCD group
  const int nt   = xcd + ((slot / 25) << 3);   // 0..31
  const int n0   = nt << 8;               // 256 rows per tile

  const int e0 = TAB.o_start[o];
  const int nE = TAB.o_start[o + 1] - e0;

  const int tid  = threadIdx.x;
  const int w    = tid >> 6;              // 0..7
  const int l    = tid & 63;

  // A staging (fp32): per issue j (0..7), rows j*32 + w*4 + (l>>4);
  // lane chunk = l&15 (16B = 4 floats); global source chunk pre-swizzled.
  // LDS dest byte = (j*32 + w*4)*256 + l*16  (wave-uniform base + lane*16).
  const int arow4 = (w << 2) + (l >> 4);          // 0..31
  const int achk  = l & 15;
  const int asrc  = ((achk ^ (arow4 & 7)) << 2);  // float offset 0..60
  const float* gAr = X + (size_t)(n0 + arow4) * (DIM * CIN) + asrc;
  float* lAr = &Asf[(size_t)arow4 * 64 + achk * 4];

  // B staging (bf16, proven r2 geometry): per issue j (0..1), rows j*64+srow
  const int srow = (w << 3) + (l >> 3);           // 0..63
  const int slt  = l & 7;
  const int ssrc = ((slt ^ (l >> 3)) << 3);       // bf16 element offset 0..56

  // compute geometry: wave grid 4 (rows) x 2 (cols), 64x64 per wave
  const int lr   = l & 15;
  const int quad = l >> 4;
  const int wr   = (w & 3) << 6;                  // 0,64,128,192
  const int wc   = (w >> 2) << 6;                 // 0,64
  const int ar   = lr & 7;                        // A-row swizzle key

  v4f acc[4][4];
  #pragma unroll
  for (int i = 0; i < 4; ++i)
    #pragma unroll
    for (int j = 0; j < 4; ++j)
      acc[i][j] = v4f{0.f, 0.f, 0.f, 0.f};

  const int nIter = nE << 1;
  for (int ki = 0; ki < nIter; ++ki) {
    const int e    = e0 + (ki >> 1);
    const int kk   = (ki & 1) << 6;            // channel half: 0 or 64
    const int irow = TAB.e_in[e];
    const int trow = TAB.e_t[e];

    const float*    gA = gAr + (size_t)irow * CIN + kk;
    const uint16_t* gB = Bt + ((size_t)trow * COUT + srow) * CIN + kk + ssrc;

    if (ki) __syncthreads();                    // prev compute done reading LDS
    // A: 8 issues x 32 rows = 256 rows (fp32); B: 2 issues x 64 rows (bf16)
    #pragma unroll
    for (int j = 0; j < 8; ++j)
      load_lds16(gA + (size_t)(j << 5) * (DIM * CIN), lAr + (j << 5) * 64);
    #pragma unroll
    for (int j = 0; j < 2; ++j) {
      const int m = (j << 6) + srow;
      load_lds16(gB + (size_t)(j << 6) * CIN, &Bs[m * 64 + slt * 8]);
    }
    __syncthreads();                            // staging visible

    #pragma unroll
    for (int kk2 = 0; kk2 < 2; ++kk2) {
      const int s8 = (kk2 << 2) + quad;         // 8-float k-slice index
      const int sb = (s8 ^ (lr & 7)) << 3;      // B chunk (bf16 elems)
      v8bf a[4], b[4];
      #pragma unroll
      for (int i = 0; i < 4; ++i) {
        const float* pa = &Asf[(wr + (i << 4) + lr) * 64];
        float4 f0 = *(const float4*)(pa + ((((s8 << 1))     ^ ar) << 2));
        float4 f1 = *(const float4*)(pa + ((((s8 << 1) | 1) ^ ar) << 2));
        a[i] = cvt8(f0, f1);
        b[i] = *(const v8bf*)(&Bs[(wc + (i << 4) + lr) * 64 + sb]);
      }
      #pragma unroll
      for (int i = 0; i < 4; ++i)
        #pragma unroll
        for (int j = 0; j < 4; ++j)
          acc[i][j] = __builtin_amdgcn_mfma_f32_16x16x32_bf16(a[i], b[j],
                                                              acc[i][j], 0, 0, 0);
    }
  }

  // epilogue: C/D layout col = lane&15 (d), row = quad*4 + r (n)
  #pragma unroll
  for (int i = 0; i < 4; ++i) {
    #pragma unroll
    for (int r = 0; r < 4; ++r) {
      const int n = n0 + wr + (i << 4) + (quad << 2) + r;
      float* op = Out + ((size_t)n * DIM + o) * COUT + wc + lr;
      #pragma unroll
      for (int j = 0; j < 4; ++j)
        op[j << 4] = acc[i][j][r];
    }
  }
}

// ---------------- launcher ---------------------------------------------------
extern "C" void kernel_launch(void* const* d_in, const int* in_sizes, int n_in,
                              void* d_out, int out_size, void* d_ws, size_t ws_size,
                              hipStream_t stream) {
  const float* X = (const float*)d_in[0];   // [8192][25][128]
  const float* W = (const float*)d_in[1];   // [85][128][128]
  float* Out = (float*)d_out;

  uint16_t* Bt = (uint16_t*)d_ws;           // 4.75 MB (only workspace use)

  // 1) tiny weight transpose/scale (fp32 -> bf16)
  prep_kernel<<<NWB, 256, 0, stream>>>(W, Bt);
  // 2) fused-dtype grouped GEMM, XCD-swizzled, 256-row tiles, LPT o-order
  so2_gemm<<<DIM * (NROWS / 256), 512, 0, stream>>>(X, Bt, Out);
}